// Round 7
// baseline (35144.022 us; speedup 1.0000x reference)
//
#include <hip/hip_runtime.h>
#include <hip/hip_cooperative_groups.h>
#include <math.h>

namespace cg = cooperative_groups;

// B=128, S=L=128, H=512, T=127 steps, SS=100.
// Persistent coop kernel, 768 WGs x 256 thr (3/CU @ 52KB LDS), pipeline depth 5:
//   round k: A(t=k) U(k-1) B(k-2) C(k-3) D(k-4), k=0..130.
// All read-only data (weights bf16, P bf16, Hst fp8) pinned in LDS -> the
// per-round device fences (cross-XCD coherence) only cost ~2MB state refetch.
//
// ws layout (bytes):
//   Pbf   ushort[16384*512]          16,777,216   inst_proj bf16, rows m=b*128+s
//   Hq8   uchar [512 wb][512 h][32s]  8,388,608   Hst fp8 e4m3, per-B-WG transposed
//   WAb   ushort[64 wg][512 k][24 j]  1,572,864   Wh1^T bf16 slices (j=v*6+ci*3+g)
//   WUb   ushort[32 wg][512 k][16 j]    524,288   Ua^T bf16  (j=v*4+q)
//   WDb   ushort[128wg][1024k][16 j]  4,194,304   [Wh2;Wi2ctx]^T bf16 (j=v*4+g, g<3)
//   A1f[3072] A2f[3072] c1f[1536] c2f[1536] (fp32 folds)
//   xselT f[256][128]
//   h1T   f[2][512][128]    ring t&1
//   uT    f[2][512][128]
//   vstack f[2][1024][128]  rows 0-511 h2, 512-1023 ctx
//   part  f[2][4][128][512] unnormalized ctx quarters
//   mzbuf f[2][4][128][2]
// total ~35.8 MB

__device__ __forceinline__ float sigm(float x){ return 1.0f/(1.0f+__expf(-x)); }
__device__ __forceinline__ float tanh_(float x){ float e=__expf(2.0f*x); return 1.0f-2.0f/(e+1.0f); }
__device__ __forceinline__ unsigned short f2bf(float x){
  unsigned u = __float_as_uint(x);
  u += 0x7FFFu + ((u>>16)&1u);
  return (unsigned short)(u>>16);
}
__device__ __forceinline__ float bflo(unsigned w){ return __uint_as_float(w<<16); }
__device__ __forceinline__ float bfhi(unsigned w){ return __uint_as_float(w & 0xFFFF0000u); }
__device__ __forceinline__ unsigned char f2e4m3(float f){
  unsigned u = __float_as_uint(f);
  unsigned s = (u>>31)<<7;
  float a = fabsf(f);
  if (!(a < 448.f)) return (unsigned char)(s|0x7E);
  if (a == 0.f) return (unsigned char)s;
  int e = (int)((u>>23)&0xFF) - 127;
  if (e < -6) {
    int qi = (int)rintf(a * 512.f);
    if (qi > 7) return (unsigned char)(s|0x08);
    return (unsigned char)(s|qi);
  }
  unsigned man = u & 0x7FFFFF;
  unsigned q = man >> 20;
  unsigned rem = man & 0xFFFFF;
  q += (rem > 0x80000u) || (rem == 0x80000u && (q&1u));
  if (q == 8){ q = 0; ++e; }
  if (e > 8 || (e == 8 && q > 6)) return (unsigned char)(s|0x7E);
  return (unsigned char)(s | (unsigned)((e+7)<<3) | q);
}
__device__ __forceinline__ float e4m3f(unsigned b){
  unsigned ef = (b>>3)&0xF, m = b&7;
  float v = ef ? __uint_as_float(((ef+120u)<<23)|(m<<20)) : (float)m*0.001953125f;
  return (b&0x80) ? -v : v;
}

// ===========================================================================
// prep: P GEMM->bf16, weight slicing->bf16, Hst->fp8, folds, xselT, zero-init
// grid 2121 x 256
// ===========================================================================
__global__ __launch_bounds__(256)
void prep_kernel(const float* __restrict__ instance, const int* __restrict__ solution,
                 const float* __restrict__ Hst, const float* __restrict__ Wr,
                 const float* __restrict__ br, const float* __restrict__ Wi1,
                 const float* __restrict__ bi1, const float* __restrict__ Wh1,
                 const float* __restrict__ Wa, const float* __restrict__ Ua,
                 const float* __restrict__ Wi2, const float* __restrict__ Wh2,
                 const float* __restrict__ bi2,
                 unsigned short* __restrict__ Pbf, unsigned char* __restrict__ Hq8,
                 unsigned short* __restrict__ WAb, unsigned short* __restrict__ WUb,
                 unsigned short* __restrict__ WDb,
                 float* __restrict__ A1f, float* __restrict__ A2f,
                 float* __restrict__ c1f, float* __restrict__ c2f,
                 float* __restrict__ xselT, float* __restrict__ h1T,
                 float* __restrict__ vstack)
{
  const int w = blockIdx.x, t = threadIdx.x;
  __shared__ float smem[6656];

  if (w < 1024) {
    // ---- P[m][h] = sum_k Hst[m][k]*Wa[h][k]; tile 128m x 64h; store bf16
    const int m0 = (w >> 3) * 128, h0 = (w & 7) * 64;
    const int hl = t & 15, mseg = t >> 4;
    float acc[4][8];
#pragma unroll
    for (int i = 0; i < 4; ++i)
#pragma unroll
      for (int r = 0; r < 8; ++r) acc[i][r] = 0.f;
    for (int kt = 0; kt < 16; ++kt) {
      { int row = t >> 1, cb = (t & 1) * 16;
        const float4* sp = (const float4*)(Hst + (size_t)(m0 + row) * 512 + kt * 32 + cb);
        float4 q0 = sp[0], q1 = sp[1], q2 = sp[2], q3 = sp[3];
        float vals[16] = {q0.x,q0.y,q0.z,q0.w,q1.x,q1.y,q1.z,q1.w,
                          q2.x,q2.y,q2.z,q2.w,q3.x,q3.y,q3.z,q3.w};
#pragma unroll
        for (int i = 0; i < 16; ++i) smem[(cb + i) * 136 + row] = vals[i]; }
      { int row = t >> 2, cb = (t & 3) * 8;
        const float4* sp = (const float4*)(Wa + (size_t)(h0 + row) * 512 + kt * 32 + cb);
        float4 q0 = sp[0], q1 = sp[1];
        float vals[8] = {q0.x,q0.y,q0.z,q0.w,q1.x,q1.y,q1.z,q1.w};
#pragma unroll
        for (int i = 0; i < 8; ++i) smem[4352 + (cb + i) * 72 + row] = vals[i]; }
      __syncthreads();
#pragma unroll 8
      for (int kk = 0; kk < 32; ++kk) {
        float4 wv = *(const float4*)&smem[4352 + kk * 72 + hl * 4];
        float4 ha = *(const float4*)&smem[kk * 136 + mseg * 8];
        float4 hb = *(const float4*)&smem[kk * 136 + mseg * 8 + 4];
        float wv_[4] = {wv.x, wv.y, wv.z, wv.w};
        float hv_[8] = {ha.x, ha.y, ha.z, ha.w, hb.x, hb.y, hb.z, hb.w};
#pragma unroll
        for (int i = 0; i < 4; ++i)
#pragma unroll
          for (int r = 0; r < 8; ++r) acc[i][r] += wv_[i] * hv_[r];
      }
      __syncthreads();
    }
#pragma unroll
    for (int r = 0; r < 8; ++r) {
      unsigned lo = (unsigned)f2bf(acc[0][r]) | ((unsigned)f2bf(acc[1][r]) << 16);
      unsigned hi = (unsigned)f2bf(acc[2][r]) | ((unsigned)f2bf(acc[3][r]) << 16);
      uint2 st = {lo, hi};
      *(uint2*)&Pbf[(size_t)(m0 + mseg * 8 + r) * 512 + h0 + hl * 4] = st;
    }

  } else if (w < 1072) {
    // ---- WAb: [wg][k][j], j=v*6+ci*3+g, c=wg*8+v*2+ci, row=c+g*512
    for (int i = 0; i < 64; ++i) {
      int e = (w - 1024) * 16384 + i * 256 + t;
      int wg = e / 12288, r = e % 12288, k = r / 24, j = r % 24;
      int v = j / 6, jj = j % 6, ci = jj / 3, g = jj % 3;
      int c = wg * 8 + v * 2 + ci;
      WAb[e] = f2bf(Wh1[(size_t)(c + g * 512) * 512 + k]);
    }
  } else if (w < 1088) {
    // ---- WUb: [wg][k][j], j=v*4+q, c=wg*16+v*4+q
    for (int i = 0; i < 64; ++i) {
      int e = (w - 1072) * 16384 + i * 256 + t;
      int wg = e / 8192, r = e % 8192, k = r / 16, j = r % 16;
      int v = j / 4, q = j % 4;
      int c = wg * 16 + v * 4 + q;
      WUb[e] = f2bf(Ua[(size_t)c * 512 + k]);
    }
  } else if (w < 1216) {
    // ---- WDb: [wg][k(1024)][j], j=v*4+g (g==3 pad), c=wg*4+v, row=c+g*512
    for (int i = 0; i < 64; ++i) {
      int e = (w - 1088) * 16384 + i * 256 + t;
      int wg = e / 16384, r = e % 16384, k = r / 16, j = r % 16;
      int v = j / 4, g = j % 4;
      float val = 0.f;
      if (g < 3) {
        int c = wg * 4 + v, row = c + g * 512;
        val = (k < 512) ? Wh2[(size_t)row * 512 + k]
                        : Wi2[(size_t)row * 1024 + 512 + (k - 512)];
      }
      WDb[e] = f2bf(val);
    }
  } else if (w < 1728) {
    // ---- Hq8: per B-WG [wb][h][s] fp8, wb=(b<<2)|q, s in quarter q
    const int wb = w - 1216, b = wb >> 2, q = wb & 3;
    for (int hh = 0; hh < 2; ++hh) {
      int h = t + hh * 256;
      unsigned dw[8];
#pragma unroll
      for (int i = 0; i < 8; ++i) dw[i] = 0u;
      for (int s = 0; s < 32; ++s) {
        float val = Hst[(size_t)(b * 128 + q * 32 + s) * 512 + h];
        dw[s >> 2] |= ((unsigned)f2e4m3(val)) << ((s & 3) * 8);
      }
      unsigned* dst = (unsigned*)(Hq8 + (size_t)wb * 16384 + (size_t)h * 32);
#pragma unroll
      for (int i = 0; i < 8; ++i) dst[i] = dw[i];
    }
  } else if (w < 2112) {
    // ---- folds: A1f/c1f from Wi1, A2f/c2f from Wi2[:, :512]; one j per wave
    const int wf = w - 1728, wv = t >> 6, lane = t & 63;
    const int j = wf * 4 + wv;
    const float4* w1p = (const float4*)(Wi1 + (size_t)j * 512 + lane * 8);
    const float4* w2p = (const float4*)(Wi2 + (size_t)j * 1024 + lane * 8);
    const float4* wrp = (const float4*)(Wr + lane * 16);
    const float4* brp = (const float4*)(br + lane * 8);
    float4 u0 = w1p[0], u1 = w1p[1], v0 = w2p[0], v1 = w2p[1];
    float4 r0 = wrp[0], r1 = wrp[1], r2 = wrp[2], r3 = wrp[3];
    float4 bb0 = brp[0], bb1 = brp[1];
    float w1a[8] = {u0.x,u0.y,u0.z,u0.w,u1.x,u1.y,u1.z,u1.w};
    float w2a[8] = {v0.x,v0.y,v0.z,v0.w,v1.x,v1.y,v1.z,v1.w};
    float wr0[8] = {r0.x,r0.z,r1.x,r1.z,r2.x,r2.z,r3.x,r3.z};
    float wr1[8] = {r0.y,r0.w,r1.y,r1.w,r2.y,r2.w,r3.y,r3.w};
    float bra[8] = {bb0.x,bb0.y,bb0.z,bb0.w,bb1.x,bb1.y,bb1.z,bb1.w};
    float a0=0,a1=0,cc=0,b0=0,b1=0,cc2=0;
#pragma unroll
    for (int i = 0; i < 8; ++i) {
      a0 += w1a[i]*wr0[i]; a1 += w1a[i]*wr1[i]; cc  += w1a[i]*bra[i];
      b0 += w2a[i]*wr0[i]; b1 += w2a[i]*wr1[i]; cc2 += w2a[i]*bra[i];
    }
#pragma unroll
    for (int off = 32; off; off >>= 1) {
      a0 += __shfl_xor(a0, off); a1 += __shfl_xor(a1, off); cc  += __shfl_xor(cc, off);
      b0 += __shfl_xor(b0, off); b1 += __shfl_xor(b1, off); cc2 += __shfl_xor(cc2, off);
    }
    if (lane == 0) {
      A1f[j*2] = a0; A1f[j*2+1] = a1; c1f[j] = cc + bi1[j];
      A2f[j*2] = b0; A2f[j*2+1] = b1; c2f[j] = cc2 + bi2[j];
    }
  } else if (w == 2112) {
    for (int o = t; o < 32768; o += 256) {
      int b = o & 127, r = o >> 7, d = r & 1, l = r >> 1;
      int sel = solution[b * 128 + l];
      xselT[o] = instance[(size_t)(b * 128 + sel) * 2 + d];
    }
  } else {
    // ---- zero h1T slot1 and vstack slot0 rows<512
    const int wz = w - 2113;
    for (int i = 0; i < 32; ++i) {
      int idx = wz * 8192 + i * 256 + t;
      h1T[65536 + idx] = 0.f;
      vstack[idx] = 0.f;
    }
  }
}

// ===========================================================================
// persistent kernel: LDS-pinned weights/P/Hst; rounds [k0,k1); coop -> grid.sync
// grid 768 x 256: A [0,64) U [64,96) B [96,608) C [608,640) D [640,768)
// ===========================================================================
__global__ void __launch_bounds__(256, 3)
persist_kernel(int k0, int k1, int coop,
               const unsigned short* __restrict__ Pbf,
               const unsigned char* __restrict__ Hq8,
               const unsigned short* __restrict__ WAb,
               const unsigned short* __restrict__ WUb,
               const unsigned short* __restrict__ WDb,
               const float* __restrict__ A1f, const float* __restrict__ A2f,
               const float* __restrict__ c1f, const float* __restrict__ c2f,
               const float* __restrict__ bh1, const float* __restrict__ bh2,
               const float* __restrict__ vvec, const float* __restrict__ xselT,
               float* __restrict__ h1T, float* __restrict__ uT,
               float* __restrict__ vstack, float* __restrict__ part,
               float* __restrict__ mzbuf)
{
  cg::grid_group grid = cg::this_grid();
  const int w = blockIdx.x, t = threadIdx.x;
  const int wv = __builtin_amdgcn_readfirstlane(t >> 6);
  const int lane = t & 63;
  __shared__ __align__(16) char LDS[53248];

  // ---------- one-time LDS staging ----------
  if (w < 64) {
    uint4* dst = (uint4*)LDS;
    const uint4* src = (const uint4*)(WAb + (size_t)w * 12288);
#pragma unroll
    for (int i = 0; i < 6; ++i) dst[i * 256 + t] = src[i * 256 + t];
    float* pA = (float*)(LDS + 24576);
    if (t < 24) {
      int v = t / 6, jj = t % 6, ci = jj / 3, g = jj % 3;
      int c = w * 8 + v * 2 + ci, row = c + g * 512;
      pA[t]      = A1f[row * 2];
      pA[24 + t] = A1f[row * 2 + 1];
      pA[48 + t] = c1f[row];
      pA[72 + t] = bh1[row];
    }
  } else if (w < 96) {
    uint4* dst = (uint4*)LDS;
    const uint4* src = (const uint4*)(WUb + (size_t)(w - 64) * 8192);
#pragma unroll
    for (int i = 0; i < 4; ++i) dst[i * 256 + t] = src[i * 256 + t];
  } else if (w < 608) {
    const int wb = w - 96, b = wb >> 2, q = wb & 3;
    uint4* dstP = (uint4*)LDS;
    const uint4* srcP = (const uint4*)(Pbf + (size_t)(b * 128 + q * 32) * 512);
#pragma unroll
    for (int i = 0; i < 8; ++i) dstP[i * 256 + t] = srcP[i * 256 + t];
    uint4* dstH = (uint4*)(LDS + 32768);
    const uint4* srcH = (const uint4*)(Hq8 + (size_t)wb * 16384);
#pragma unroll
    for (int i = 0; i < 4; ++i) dstH[i * 256 + t] = srcH[i * 256 + t];
    unsigned short* vS = (unsigned short*)(LDS + 51200);
    vS[t] = f2bf(vvec[t]); vS[t + 256] = f2bf(vvec[t + 256]);
  } else if (w >= 640) {
    const int wd = w - 640;
    uint4* dst = (uint4*)LDS;
    const uint4* src = (const uint4*)(WDb + (size_t)wd * 16384);
#pragma unroll
    for (int i = 0; i < 8; ++i) dst[i * 256 + t] = src[i * 256 + t];
    float* pD = (float*)(LDS + 32768);
    if (t < 16) {
      int v = t >> 2, g = t & 3;
      float ax = 0, ay = 0, cs = 0, bz = 0;
      if (g < 3) {
        int c = wd * 4 + v, row = c + g * 512;
        ax = A2f[row * 2]; ay = A2f[row * 2 + 1]; cs = c2f[row]; bz = bh2[row];
      }
      pD[t] = ax; pD[16 + t] = ay; pD[32 + t] = cs; pD[48 + t] = bz;
    }
  }
  __syncthreads();

  // ---------- pipelined rounds ----------
  for (int k = k0; k < k1; ++k) {
    if (w < 64) {
      // ===== A: GRU1; wave owns 2 cols, full K=512 =====
      const int tA = k;
      if (tA <= 126) {
        const int slotW = tA & 1, slotR = slotW ^ 1;
        const unsigned short* wA = (const unsigned short*)LDS;
        const float* pA = (const float*)(LDS + 24576);
        const float* hp = h1T + slotR * 65536 + lane * 2;
        float acc[12];
#pragma unroll
        for (int i = 0; i < 12; ++i) acc[i] = 0.f;
        const int jb = wv * 6;
#pragma unroll 4
        for (int kk = 0; kk < 512; ++kk) {
          float2 hv = *(const float2*)(hp + kk * 128);
          const unsigned short* wr = wA + kk * 24 + jb;
          unsigned w01 = *(const unsigned*)(wr);
          unsigned w23 = *(const unsigned*)(wr + 2);
          unsigned w45 = *(const unsigned*)(wr + 4);
          float f0 = bflo(w01), f1 = bfhi(w01);
          float f2 = bflo(w23), f3 = bfhi(w23);
          float f4 = bflo(w45), f5 = bfhi(w45);
          acc[0] += hv.x*f0; acc[1] += hv.y*f0;
          acc[2] += hv.x*f1; acc[3] += hv.y*f1;
          acc[4] += hv.x*f2; acc[5] += hv.y*f2;
          acc[6] += hv.x*f3; acc[7] += hv.y*f3;
          acc[8] += hv.x*f4; acc[9] += hv.y*f4;
          acc[10]+= hv.x*f5; acc[11]+= hv.y*f5;
        }
#pragma unroll
        for (int ci = 0; ci < 2; ++ci) {
#pragma unroll
          for (int bs = 0; bs < 2; ++bs) {
            int b = lane * 2 + bs;
            int j0 = jb + ci * 3;
            float gr = acc[(ci*3+0)*2+bs];
            float gz = acc[(ci*3+1)*2+bs];
            float gn = acc[(ci*3+2)*2+bs];
            float x0 = xselT[(tA*2)*128 + b], x1 = xselT[(tA*2+1)*128 + b];
            float ir  = pA[j0  ]*x0 + pA[24+j0  ]*x1 + pA[48+j0  ];
            float iz  = pA[j0+1]*x0 + pA[24+j0+1]*x1 + pA[48+j0+1];
            float in_ = pA[j0+2]*x0 + pA[24+j0+2]*x1 + pA[48+j0+2];
            float r = sigm(ir + gr + pA[72+j0]);
            float z = sigm(iz + gz + pA[72+j0+1]);
            float n = tanh_(in_ + r * (gn + pA[72+j0+2]));
            int c = w * 8 + wv * 2 + ci;
            float hprev = h1T[slotR * 65536 + c * 128 + b];
            h1T[slotW * 65536 + c * 128 + b] = (1.f - z) * n + z * hprev;
          }
        }
      }
    } else if (w < 96) {
      // ===== U: u = h1 @ Ua^T; wave owns 4 cols, full K =====
      const int tU = k - 1;
      if (tU >= 0 && tU <= 126) {
        const int slot = tU & 1;
        const unsigned short* wU = (const unsigned short*)LDS;
        const float* hp = h1T + slot * 65536 + lane * 2;
        float acc[8];
#pragma unroll
        for (int i = 0; i < 8; ++i) acc[i] = 0.f;
        const int jb = wv * 4;
#pragma unroll 4
        for (int kk = 0; kk < 512; ++kk) {
          float2 hv = *(const float2*)(hp + kk * 128);
          const unsigned short* wr = wU + kk * 16 + jb;
          unsigned w01 = *(const unsigned*)(wr);
          unsigned w23 = *(const unsigned*)(wr + 2);
          float f0 = bflo(w01), f1 = bfhi(w01);
          float f2 = bflo(w23), f3 = bfhi(w23);
          acc[0]+=hv.x*f0; acc[1]+=hv.y*f0;
          acc[2]+=hv.x*f1; acc[3]+=hv.y*f1;
          acc[4]+=hv.x*f2; acc[5]+=hv.y*f2;
          acc[6]+=hv.x*f3; acc[7]+=hv.y*f3;
        }
        int c0 = (w - 64) * 16 + wv * 4;
#pragma unroll
        for (int qq = 0; qq < 4; ++qq) {
          float2 st = {acc[qq*2], acc[qq*2+1]};
          *(float2*)(uT + slot * 65536 + (c0 + qq) * 128 + lane * 2) = st;
        }
      }
    } else if (w < 608) {
      // ===== B: scores + partial softmax + partial context (LDS P/Hst) =====
      const int tB = k - 2;
      if (tB >= 0 && tB <= 126) {
        const int wb = w - 96, b = wb >> 2, q = wb & 3, slot = tB & 1;
        const unsigned short* Pq = (const unsigned short*)LDS;
        const unsigned* Hq = (const unsigned*)(LDS + 32768);
        float* uS = (float*)(LDS + 49152);
        const unsigned short* vS = (const unsigned short*)(LDS + 51200);
        float* scS = (float*)(LDS + 52224);
        float* wgt = (float*)(LDS + 52352);
        uS[t]       = uT[slot * 65536 + t * 128 + b];
        uS[t + 256] = uT[slot * 65536 + (t + 256) * 128 + b];
        __syncthreads();
        const int h0 = lane * 8;
#pragma unroll
        for (int si = 0; si < 8; ++si) {
          int s = wv * 8 + si;
          uint4 pw = *(const uint4*)(Pq + s * 512 + h0);
          float4 ua = *(const float4*)(uS + h0);
          float4 ub = *(const float4*)(uS + h0 + 4);
          uint4 vw = *(const uint4*)(vS + h0);
          float val =
              tanh_(bflo(pw.x)+ua.x)*bflo(vw.x) + tanh_(bfhi(pw.x)+ua.y)*bfhi(vw.x)
            + tanh_(bflo(pw.y)+ua.z)*bflo(vw.y) + tanh_(bfhi(pw.y)+ua.w)*bfhi(vw.y)
            + tanh_(bflo(pw.z)+ub.x)*bflo(vw.z) + tanh_(bfhi(pw.z)+ub.y)*bfhi(vw.z)
            + tanh_(bflo(pw.w)+ub.z)*bflo(vw.w) + tanh_(bfhi(pw.w)+ub.w)*bfhi(vw.w);
#pragma unroll
          for (int off = 32; off; off >>= 1) val += __shfl_xor(val, off);
          if (lane == 0) scS[s] = val;
        }
        __syncthreads();
        if (t < 32) {
          float sc = scS[t], m = sc;
#pragma unroll
          for (int off = 16; off; off >>= 1) m = fmaxf(m, __shfl_xor(m, off));
          float e = __expf(sc - m), zz = e;
#pragma unroll
          for (int off = 16; off; off >>= 1) zz += __shfl_xor(zz, off);
          wgt[t] = e;
          if (t == 0) {
            int mzi = ((slot * 4 + q) * 128 + b) * 2;
            mzbuf[mzi] = m; mzbuf[mzi + 1] = zz;
          }
        }
        __syncthreads();
#pragma unroll
        for (int hh = 0; hh < 2; ++hh) {
          int h = t + hh * 256;
          const unsigned* hr = Hq + h * 8;
          float a = 0.f;
#pragma unroll
          for (int dw = 0; dw < 8; ++dw) {
            unsigned u = hr[dw];
            a += wgt[dw*4+0] * e4m3f(u & 0xFFu)
               + wgt[dw*4+1] * e4m3f((u >> 8) & 0xFFu)
               + wgt[dw*4+2] * e4m3f((u >> 16) & 0xFFu)
               + wgt[dw*4+3] * e4m3f(u >> 24);
          }
          part[((size_t)(slot * 4 + q) * 128 + b) * 512 + h] = a;
        }
      }
    } else if (w < 640) {
      // ===== C: combine softmax quarters -> ctx rows of vstack =====
      const int tC = k - 3;
      if (tC >= 0 && tC <= 126) {
        const int wc = w - 608, b0 = wc * 4, slot = tC & 1;
        float* scaleS = (float*)LDS;
        if (t < 4) {
          int bb = b0 + t;
          float m0 = mzbuf[((slot*4+0)*128+bb)*2], z0 = mzbuf[((slot*4+0)*128+bb)*2+1];
          float m1 = mzbuf[((slot*4+1)*128+bb)*2], z1 = mzbuf[((slot*4+1)*128+bb)*2+1];
          float m2 = mzbuf[((slot*4+2)*128+bb)*2], z2 = mzbuf[((slot*4+2)*128+bb)*2+1];
          float m3 = mzbuf[((slot*4+3)*128+bb)*2], z3 = mzbuf[((slot*4+3)*128+bb)*2+1];
          float M = fmaxf(fmaxf(m0, m1), fmaxf(m2, m3));
          float e0 = __expf(m0-M), e1 = __expf(m1-M), e2 = __expf(m2-M), e3 = __expf(m3-M);
          float inv = 1.f / (z0*e0 + z1*e1 + z2*e2 + z3*e3);
          scaleS[t*4+0] = e0*inv; scaleS[t*4+1] = e1*inv;
          scaleS[t*4+2] = e2*inv; scaleS[t*4+3] = e3*inv;
        }
        __syncthreads();
#pragma unroll
        for (int hh = 0; hh < 2; ++hh) {
          int h = t + hh * 256;
          float o[4];
#pragma unroll
          for (int bb = 0; bb < 4; ++bb) {
            o[bb] = scaleS[bb*4+0] * part[((size_t)(slot*4+0)*128 + b0+bb)*512 + h]
                  + scaleS[bb*4+1] * part[((size_t)(slot*4+1)*128 + b0+bb)*512 + h]
                  + scaleS[bb*4+2] * part[((size_t)(slot*4+2)*128 + b0+bb)*512 + h]
                  + scaleS[bb*4+3] * part[((size_t)(slot*4+3)*128 + b0+bb)*512 + h];
          }
          float4 st = {o[0], o[1], o[2], o[3]};
          *(float4*)(vstack + slot * 131072 + (512 + h) * 128 + b0) = st;
        }
        __syncthreads();
      }
    } else {
      // ===== D: GRU2 over [h2; ctx] K=1024; wave owns 1 col =====
      const int tD = k - 4;
      if (tD >= 0 && tD <= 126) {
        const int wd = w - 640, slot = tD & 1, nslot = slot ^ 1;
        const unsigned short* wD = (const unsigned short*)LDS;
        const float* pD = (const float*)(LDS + 32768);
        const float* vsp = vstack + slot * 131072;
        const float* hp = vsp + lane * 2;
        float acc[8];
#pragma unroll
        for (int i = 0; i < 8; ++i) acc[i] = 0.f;
        const int jb = wv * 4;
#pragma unroll 4
        for (int kk = 0; kk < 512; ++kk) {
          float2 hv = *(const float2*)(hp + kk * 128);
          const unsigned short* wr = wD + kk * 16 + jb;
          unsigned w01 = *(const unsigned*)(wr);
          unsigned w23 = *(const unsigned*)(wr + 2);
          float fr = bflo(w01), fz = bfhi(w01), fn = bflo(w23);
          acc[0]+=hv.x*fr; acc[1]+=hv.y*fr;
          acc[2]+=hv.x*fz; acc[3]+=hv.y*fz;
          acc[4]+=hv.x*fn; acc[5]+=hv.y*fn;
        }
#pragma unroll 4
        for (int kk = 512; kk < 1024; ++kk) {
          float2 hv = *(const float2*)(hp + kk * 128);
          const unsigned short* wr = wD + kk * 16 + jb;
          unsigned w01 = *(const unsigned*)(wr);
          unsigned w23 = *(const unsigned*)(wr + 2);
          float fr = bflo(w01), fz = bfhi(w01), fn = bflo(w23);
          acc[0]+=hv.x*fr; acc[1]+=hv.y*fr;
          acc[2]+=hv.x*fz; acc[3]+=hv.y*fz;
          acc[6]+=hv.x*fn; acc[7]+=hv.y*fn;
        }
        int c = wd * 4 + wv;
#pragma unroll
        for (int bs = 0; bs < 2; ++bs) {
          int b = lane * 2 + bs;
          float x0 = xselT[((tD+1)*2)*128 + b], x1 = xselT[((tD+1)*2+1)*128 + b];
          int j = jb;
          float ir = pD[j  ]*x0 + pD[16+j  ]*x1 + pD[32+j  ] + acc[0+bs] + pD[48+j  ];
          float iz = pD[j+1]*x0 + pD[16+j+1]*x1 + pD[32+j+1] + acc[2+bs] + pD[48+j+1];
          float r = sigm(ir), z = sigm(iz);
          float in_ = pD[j+2]*x0 + pD[16+j+2]*x1 + pD[32+j+2] + acc[6+bs];
          float n = tanh_(in_ + r * (acc[4+bs] + pD[48+j+2]));
          float hprev = vsp[c * 128 + b];
          vstack[nslot * 131072 + c * 128 + b] = (1.f - z) * n + z * hprev;
        }
      }
    }
    if (coop) { __threadfence(); grid.sync(); __threadfence(); }
  }
}

// ===========================================================================
// epilogue: mu/logvar/z from h2(126) (vstack slot 1, rows 0..511)
// ===========================================================================
__global__ __launch_bounds__(128)
void final_kernel(const float* __restrict__ vstack, const float* __restrict__ eps,
                  const float* __restrict__ W1, const float* __restrict__ b1,
                  const float* __restrict__ W2, const float* __restrict__ b2,
                  float* __restrict__ out)
{
  const int b = blockIdx.x, t = threadIdx.x;
  __shared__ float hS[512];
  const float* h2 = vstack + 131072;
  for (int i = t; i < 512; i += 128) hS[i] = h2[i * 128 + b];
  __syncthreads();
  if (t < 100) {
    const float* w1 = W1 + (size_t)t * 512;
    const float* w2 = W2 + (size_t)t * 512;
    float mu = b1[t], lv = b2[t];
    for (int kk = 0; kk < 512; ++kk) { float h = hS[kk]; mu += h * w1[kk]; lv += h * w2[kk]; }
    float zz = mu + eps[b * 100 + t] * __expf(0.5f * lv);
    out[b * 100 + t] = zz;
    out[12800 + b * 100 + t] = mu;
    out[25600 + b * 100 + t] = lv;
  }
}

// ===========================================================================
extern "C" void kernel_launch(void* const* d_in, const int* in_sizes, int n_in,
                              void* d_out, int out_size, void* d_ws, size_t ws_size,
                              hipStream_t stream)
{
  const float* instance = (const float*)d_in[0];
  const int*   solution = (const int*)d_in[1];
  const float* Hst      = (const float*)d_in[2];
  const float* eps      = (const float*)d_in[3];
  const float* Wr  = (const float*)d_in[4];
  const float* br  = (const float*)d_in[5];
  const float* Wi1 = (const float*)d_in[6];
  const float* Wh1 = (const float*)d_in[7];
  const float* bi1 = (const float*)d_in[8];
  const float* bh1 = (const float*)d_in[9];
  const float* Wa  = (const float*)d_in[10];
  const float* Ua  = (const float*)d_in[11];
  const float* v   = (const float*)d_in[12];
  const float* Wi2 = (const float*)d_in[13];
  const float* Wh2 = (const float*)d_in[14];
  const float* bi2 = (const float*)d_in[15];
  const float* bh2 = (const float*)d_in[16];
  const float* W1  = (const float*)d_in[17];
  const float* b1  = (const float*)d_in[18];
  const float* W2  = (const float*)d_in[19];
  const float* b2  = (const float*)d_in[20];

  char* base = (char*)d_ws;
  unsigned short* Pbf = (unsigned short*)base;                 // 16,777,216 B
  unsigned char*  Hq8 = (unsigned char*)(base + 16777216);     //  8,388,608 B
  unsigned short* WAb = (unsigned short*)(base + 25165824);    //  1,572,864 B
  unsigned short* WUb = (unsigned short*)(base + 26738688);    //    524,288 B
  unsigned short* WDb = (unsigned short*)(base + 27262976);    //  4,194,304 B
  float* A1f   = (float*)(base + 31457280);                    // 3072 f
  float* A2f   = A1f + 3072;
  float* c1f   = A2f + 3072;
  float* c2f   = c1f + 1536;
  float* xselT = c2f + 1536;       // 32768 f
  float* h1T   = xselT + 32768;    // 131072 f
  float* uT    = h1T + 131072;     // 131072 f
  float* vstack= uT + 131072;      // 262144 f
  float* part  = vstack + 262144;  // 524288 f
  float* mzbuf = part + 524288;    // 2048 f   (total ~35.8 MB)

  prep_kernel<<<dim3(2121), dim3(256), 0, stream>>>(
      instance, solution, Hst, Wr, br, Wi1, bi1, Wh1, Wa, Ua, Wi2, Wh2, bi2,
      Pbf, Hq8, WAb, WUb, WDb, A1f, A2f, c1f, c2f, xselT, h1T, vstack);

  int k0v = 0, k1v = 131, coopv = 1;
  const unsigned short *Pbf_ = Pbf, *WAb_ = WAb, *WUb_ = WUb, *WDb_ = WDb;
  const unsigned char *Hq8_ = Hq8;
  const float *A1f_ = A1f, *A2f_ = A2f, *c1f_ = c1f, *c2f_ = c2f;
  const float *bh1_ = bh1, *bh2_ = bh2, *v_ = v, *xselT_ = xselT;
  float *h1T_ = h1T, *uT_ = uT, *vstack_ = vstack, *part_ = part, *mzbuf_ = mzbuf;
  void* args[] = {&k0v, &k1v, &coopv,
                  (void*)&Pbf_, (void*)&Hq8_, (void*)&WAb_, (void*)&WUb_, (void*)&WDb_,
                  (void*)&A1f_, (void*)&A2f_, (void*)&c1f_, (void*)&c2f_,
                  (void*)&bh1_, (void*)&bh2_, (void*)&v_, (void*)&xselT_,
                  (void*)&h1T_, (void*)&uT_, (void*)&vstack_, (void*)&part_,
                  (void*)&mzbuf_};
  hipError_t rc = hipLaunchCooperativeKernel((void*)persist_kernel, dim3(768),
                                             dim3(256), args, 0, stream);
  if (rc != hipSuccess) {
    // fallback: one round per launch (kernel boundary = sync + coherence)
    for (int k = 0; k < 131; ++k)
      persist_kernel<<<dim3(768), dim3(256), 0, stream>>>(
          k, k + 1, 0, Pbf, Hq8, WAb, WUb, WDb, A1f, A2f, c1f, c2f,
          bh1, bh2, v, xselT, h1T, uT, vstack, part, mzbuf);
  }

  final_kernel<<<dim3(128), dim3(128), 0, stream>>>(vstack, eps, W1, b1, W2, b2, (float*)d_out);
}